// Round 7
// baseline (483.443 us; speedup 1.0000x reference)
//
#include <hip/hip_runtime.h>
#include <hip/hip_bf16.h>
#include <stdint.h>

#define N_ROWS 200000
#define C_DIM  128
#define TAPS   27
#define EPS    1e-5f

typedef __attribute__((ext_vector_type(8)))  short  short8;
typedef __attribute__((ext_vector_type(16))) float  floatx16;

// ---- gather path: sc0 buffer loads (r3: neutral perf, fewer addr VGPRs) ----
#if __has_builtin(__builtin_amdgcn_make_buffer_rsrc) && __has_builtin(__builtin_amdgcn_raw_buffer_load_b128)
#define GATHER_SC0 1
#else
#define GATHER_SC0 0
#endif

#define SBAR()  __builtin_amdgcn_s_barrier()
#define SCHED() __builtin_amdgcn_sched_barrier(0)

__device__ __forceinline__ unsigned int f2bf(float f) {
  union { float f; unsigned int u; } v; v.f = f;
  unsigned int r = v.u + 0x7FFFu + ((v.u >> 16) & 1u);   // RNE, inputs finite
  return r >> 16;
}

__device__ __forceinline__ void glds16(const unsigned short* g, unsigned short* l) {
  __builtin_amdgcn_global_load_lds(
      (const __attribute__((address_space(1))) unsigned int*)g,
      (__attribute__((address_space(3))) unsigned int*)l, 16, 0, 0);
}

#if GATHER_SC0
__device__ __forceinline__ short8 ld16sc0(__amdgpu_buffer_rsrc_t r, int voff) {
  return __builtin_bit_cast(short8,
      __builtin_amdgcn_raw_buffer_load_b128(r, voff, 0, 1));
}
#endif

// ---------------- feats fp32 -> bf16 ----------------
__global__ __launch_bounds__(256) void k_cast(const float* __restrict__ in,
                                              unsigned short* __restrict__ out, int n8) {
  int i = blockIdx.x * 256 + threadIdx.x;
  if (i >= n8) return;
  const float4* p = (const float4*)in + (size_t)i * 2;
  float4 a = p[0], b = p[1];
  uint4 v;
  v.x = f2bf(a.x) | (f2bf(a.y) << 16);
  v.y = f2bf(a.z) | (f2bf(a.w) << 16);
  v.z = f2bf(b.x) | (f2bf(b.y) << 16);
  v.w = f2bf(b.z) | (f2bf(b.w) << 16);
  *(uint4*)(out + (size_t)i * 8) = v;
}

// ---------------- nidx [N][27] -> nidxT [27][N] ----------------
__global__ __launch_bounds__(256) void k_tr(const int* __restrict__ in,
                                            int* __restrict__ outT) {
  __shared__ int t[1728];
  const int tile = blockIdx.x;                 // 3125 tiles x 64 rows (exact)
  const int* src = in + (size_t)tile * 1728;
  for (int e = threadIdx.x; e < 1728; e += 256) t[e] = src[e];
  __syncthreads();
  const int base = tile * 64;
  for (int o = threadIdx.x; o < 1728; o += 256) {
    int k = o >> 6, r = o & 63;
    outT[(size_t)k * N_ROWS + base + r] = t[r * 27 + k];
  }
}

// ---- fold Linear into conv weights; emit MFMA B-fragment layout ----
// r7 layout: wfrag[k][qr(4)][nt(4)][sh(2)][lane(64)][j(8)] (bf16): each K=32
// QUARTER of a tap (4096 shorts = 8 KB) contiguous for ring staging.
//   s = qr*2+sh ; kk_global = s*16 + (l>>5)*8 + j ; co = nt*32 + (l&31)
__global__ __launch_bounds__(256) void k_fold(const float* __restrict__ conv_w,
                                              const float* __restrict__ lin_w,
                                              const float* __restrict__ conv_b,
                                              const float* __restrict__ lin_b,
                                              unsigned short* __restrict__ wfrag,
                                              float* __restrict__ biasf) {
  __shared__ float lwT[128 * 128];  // 64 KB
  for (int e = threadIdx.x; e < 16384; e += 256) {
    int co = e >> 7, t = e & 127;
    lwT[t * 128 + (co ^ (t & 31))] = lin_w[e];
  }
  __syncthreads();

  int id = blockIdx.x * 256 + threadIdx.x;
  const int NW = TAPS * 4 * 4 * 2 * 64;  // 55296
  if (id < NW) {
    int l  = id & 63;
    int sh = (id >> 6) & 1;
    int nt = (id >> 7) & 3;
    int qr = (id >> 9) & 3;
    int k  = id >> 11;
    int s  = qr * 2 + sh;
    int ci0 = s * 16 + (l >> 5) * 8;
    int co  = nt * 32 + (l & 31);
    const float* cw = conv_w + ((size_t)(k * 128 + ci0)) * 128;
    float acc[8] = {0, 0, 0, 0, 0, 0, 0, 0};
    for (int t = 0; t < 128; ++t) {
      float lv = lwT[t * 128 + (co ^ (t & 31))];
#pragma unroll
      for (int j = 0; j < 8; ++j) acc[j] += cw[j * 128 + t] * lv;
    }
    uint4 v;
    v.x = f2bf(acc[0]) | (f2bf(acc[1]) << 16);
    v.y = f2bf(acc[2]) | (f2bf(acc[3]) << 16);
    v.z = f2bf(acc[4]) | (f2bf(acc[5]) << 16);
    v.w = f2bf(acc[6]) | (f2bf(acc[7]) << 16);
    *(uint4*)(wfrag + (size_t)id * 8) = v;
  } else if (id < NW + 128) {
    int co = id - NW;
    float s = lin_b[co];
    for (int t = 0; t < 128; ++t) s += conv_b[t] * lwT[t * 128 + (co ^ (t & 31))];
    biasf[co] = s;
  }
}

// ---------------- fused gather-GEMM + LayerNorm ----------------
// r7: r6 geometry (4 waves, 128 rows/block, 4 blocks/CU) with a 108-step
// counted-vmcnt ring pipeline (T3/T4):
//   * 4-slot LDS ring (4 x 8 KB), slot = quarter Q % 4 (compile-time).
//   * Step q=(t,p): wait -> barrier -> issue [A-pair + nid] -> [glds Q(q+3)]
//     -> 8 ds_read + 8 MFMA. One barrier/step (108 total, = r6's count).
//   * B lead 3 steps (~450cy), A lead 3 steps (in-place pair rotation, zero
//     extra VGPR), nid lead 5-8 steps (3-reg rotation). Never drain vmcnt.
//   * Waits retire exactly the full issue-group from 3 steps back (robust to
//     intra-cluster reorder); A-cluster precedes G-cluster in FIFO (SCHED-
//     pinned) so retiring A never forces a younger-quarter glds early.
//   * FIFO ledger (steady, t>=1): step sizes p0..p3 = 5,4,4,4 (17/tap).
//     p0: keep (t-1,p2)+(t-1,p3)=8 ; p1: keep (t-1,p3)+(t,p0)=9 ;
//     p2: keep (t,p0)+(t,p1)=9     ; p3: keep (t,p1)+(t,p2)=8.
//     t=0 (post-prologue-drain, 6 A-loads outstanding): p0=4, p1=7, p2/p3
//     already equal steady values.
//   * rule #18: sched_barrier(0) before every s_barrier (r5-verified).
__global__ __launch_bounds__(256, 4) void k_main(const unsigned short* __restrict__ featsB,
                                                 const int* __restrict__ ntab,
                                                 const int nrs, const int nts,
                                                 const unsigned short* __restrict__ wfrag,
                                                 const float* __restrict__ biasf,
                                                 const float* __restrict__ lnw,
                                                 const float* __restrict__ lnb,
                                                 float* __restrict__ out) {
  __shared__ unsigned short lds4[4][4096];  // 4 x 8 KB ring

  const int tid = threadIdx.x;
  const int l   = tid & 63;
  const int w   = tid >> 6;          // 0..3
  const int l31 = l & 31;
  const int lh  = l >> 5;
  const int row0w = blockIdx.x * 128 + w * 32;
  const int gr  = row0w + l31;
  const int grc = (gr < N_ROWS) ? gr : 0;
  const int* np = ntab + (size_t)grc * nrs;

#if GATHER_SC0
  __amdgpu_buffer_rsrc_t rsrc = __builtin_amdgcn_make_buffer_rsrc(
      (void*)featsB, (short)0, N_ROWS * C_DIM * 2, 0x00020000);
#define A_LD(vo) ld16sc0(rsrc, (vo))
#else
#define A_LD(vo) (*(const short8*)((const char*)featsB + (vo)))
#endif

// stage quarter Qi into ring slot `slot` (2 glds/thread; Qi%4 == slot)
#define STAGE(Qi, slot) do {                                                 \
    int Qc = (Qi) > 4 * TAPS - 1 ? 4 * TAPS - 1 : (Qi);                      \
    const unsigned short* s_ = wfrag + (size_t)Qc * 4096 + tid * 8;          \
    unsigned short* d_ = &lds4[slot][w * 512];                               \
    glds16(s_, d_);                                                          \
    glds16(s_ + 2048, d_ + 2048);                                            \
  } while (0)

// compute one K=32 quarter from ring slot: 8 ds_read_b128 + 8 MFMA
#define COMPQ(slot, avA, avB) do {                                           \
    const unsigned short* bb = &lds4[slot][l * 8];                           \
    short8 c0 = *(const short8*)(bb + 0);                                    \
    short8 c1 = *(const short8*)(bb + 1024);                                 \
    short8 c2 = *(const short8*)(bb + 2048);                                 \
    short8 c3 = *(const short8*)(bb + 3072);                                 \
    acc0 = __builtin_amdgcn_mfma_f32_32x32x16_bf16(avA, c0, acc0, 0, 0, 0);  \
    acc1 = __builtin_amdgcn_mfma_f32_32x32x16_bf16(avA, c1, acc1, 0, 0, 0);  \
    acc2 = __builtin_amdgcn_mfma_f32_32x32x16_bf16(avA, c2, acc2, 0, 0, 0);  \
    acc3 = __builtin_amdgcn_mfma_f32_32x32x16_bf16(avA, c3, acc3, 0, 0, 0);  \
    short8 d0 = *(const short8*)(bb + 512);                                  \
    short8 d1 = *(const short8*)(bb + 1536);                                 \
    short8 d2 = *(const short8*)(bb + 2560);                                 \
    short8 d3 = *(const short8*)(bb + 3584);                                 \
    acc0 = __builtin_amdgcn_mfma_f32_32x32x16_bf16(avB, d0, acc0, 0, 0, 0);  \
    acc1 = __builtin_amdgcn_mfma_f32_32x32x16_bf16(avB, d1, acc1, 0, 0, 0);  \
    acc2 = __builtin_amdgcn_mfma_f32_32x32x16_bf16(avB, d2, acc2, 0, 0, 0);  \
    acc3 = __builtin_amdgcn_mfma_f32_32x32x16_bf16(avB, d3, acc3, 0, 0, 0);  \
  } while (0)

  floatx16 acc0 = {0.f}, acc1 = {0.f}, acc2 = {0.f}, acc3 = {0.f};

  // ---- prologue: stage Q0..Q2; load nid0,nid1; drain; issue A(0)[0..5] ----
  STAGE(0, 0);
  STAGE(1, 1);
  STAGE(2, 2);
  int nid_cur = np[0];
  int nid_nxt = np[nts];
  int nid_fut;
  __builtin_amdgcn_s_waitcnt(0xF70);  // one-time full drain (Q0-2 + nids)
  SCHED();
  short8 a0, a1, a2, a3, a4, a5, a6, a7;
  {
    const int vo = ((int)(unsigned)nid_cur << 8) + (lh << 4);
    a0 = A_LD(vo);
    a1 = A_LD(vo + 32);
    a2 = A_LD(vo + 64);
    a3 = A_LD(vo + 96);
    a4 = A_LD(vo + 128);
    a5 = A_LD(vo + 160);
  }
  SCHED();

  for (int t = 0; t < TAPS; ++t) {
    // ================= p=0: reads slot 0 (Q=4t) =================
    if (t == 0) __builtin_amdgcn_s_waitcnt(0xF74);   // vmcnt(4): a0,a1 landed
    else        __builtin_amdgcn_s_waitcnt(0xF78);   // vmcnt(8): retire (t-1,p1)
    SCHED(); SBAR(); SCHED();
    {
      const int tf = (t + 2 < TAPS) ? (t + 2) : (TAPS - 1);
      nid_fut = np[(size_t)tf * nts];
      const int vo = ((int)(unsigned)nid_cur << 8) + (lh << 4);
      a6 = A_LD(vo + 192);
      a7 = A_LD(vo + 224);
    }
    SCHED();
    STAGE(4 * t + 3, 3);
    SCHED();
    COMPQ(0, a0, a1);

    // ================= p=1: reads slot 1 (Q=4t+1) =================
    if (t == 0) __builtin_amdgcn_s_waitcnt(0xF77);   // vmcnt(7): a2,a3 landed
    else        __builtin_amdgcn_s_waitcnt(0xF79);   // vmcnt(9): retire (t-1,p2)
    SCHED(); SBAR(); SCHED();
    {
      const int vo = ((int)(unsigned)nid_nxt << 8) + (lh << 4);
      a0 = A_LD(vo);
      a1 = A_LD(vo + 32);
    }
    SCHED();
    STAGE(4 * t + 4, 0);
    SCHED();
    COMPQ(1, a2, a3);

    // ================= p=2: reads slot 2 (Q=4t+2) =================
    __builtin_amdgcn_s_waitcnt(0xF79);               // vmcnt(9): retire (t-1,p3)
    SCHED(); SBAR(); SCHED();
    {
      const int vo = ((int)(unsigned)nid_nxt << 8) + (lh << 4);
      a2 = A_LD(vo + 64);
      a3 = A_LD(vo + 96);
    }
    SCHED();
    STAGE(4 * t + 5, 1);
    SCHED();
    COMPQ(2, a4, a5);

    // ================= p=3: reads slot 3 (Q=4t+3) =================
    __builtin_amdgcn_s_waitcnt(0xF78);               // vmcnt(8): retire (t,p0)
    SCHED(); SBAR(); SCHED();
    {
      const int vo = ((int)(unsigned)nid_nxt << 8) + (lh << 4);
      a4 = A_LD(vo + 128);
      a5 = A_LD(vo + 160);
    }
    SCHED();
    STAGE(4 * t + 6, 2);
    SCHED();
    COMPQ(3, a6, a7);

    nid_cur = nid_nxt;
    nid_nxt = nid_fut;
  }
  // leftover in-flight loads (tail prefetches) retire naturally; no drain.

  // ---- epilogue: bias + in-wave LayerNorm + store ----
  float b0 = biasf[l31], b1 = biasf[32 + l31], b2 = biasf[64 + l31], b3 = biasf[96 + l31];
  float g0 = lnw[l31],   g1 = lnw[32 + l31],   g2 = lnw[64 + l31],   g3 = lnw[96 + l31];
  float c0 = lnb[l31],   c1 = lnb[32 + l31],   c2 = lnb[64 + l31],   c3 = lnb[96 + l31];

#pragma unroll
  for (int r = 0; r < 16; ++r) {
    float x0 = acc0[r] + b0, x1 = acc1[r] + b1, x2 = acc2[r] + b2, x3 = acc3[r] + b3;
    float s = x0 + x1 + x2 + x3;
    float q = x0 * x0 + x1 * x1 + x2 * x2 + x3 * x3;
#pragma unroll
    for (int off = 16; off >= 1; off >>= 1) {
      s += __shfl_xor(s, off, 64);
      q += __shfl_xor(q, off, 64);
    }
    float mu  = s * (1.0f / 128.0f);
    float var = q * (1.0f / 128.0f) - mu * mu;
    float rs  = rsqrtf(var + EPS);
    int row   = (r & 3) + 8 * (r >> 2) + 4 * lh;  // 32x32 C/D row map
    int grow  = row0w + row;
    if (grow < N_ROWS) {
      float* o = out + (size_t)grow * 128;
      o[l31]      = (x0 - mu) * rs * g0 + c0;
      o[32 + l31] = (x1 - mu) * rs * g1 + c1;
      o[64 + l31] = (x2 - mu) * rs * g2 + c2;
      o[96 + l31] = (x3 - mu) * rs * g3 + c3;
    }
  }
}

extern "C" void kernel_launch(void* const* d_in, const int* in_sizes, int n_in,
                              void* d_out, int out_size, void* d_ws, size_t ws_size,
                              hipStream_t stream) {
  const float* feats  = (const float*)d_in[0];
  const int*   nidx   = (const int*)d_in[1];
  const float* conv_w = (const float*)d_in[2];
  const float* conv_b = (const float*)d_in[3];
  const float* lin_w  = (const float*)d_in[4];
  const float* lin_b  = (const float*)d_in[5];
  const float* ln_w   = (const float*)d_in[6];
  const float* ln_b   = (const float*)d_in[7];
  float* out = (float*)d_out;

  unsigned short* featsB = (unsigned short*)d_ws;                       // 51,200,000 B
  unsigned short* wfrag  = (unsigned short*)((char*)d_ws + 51200000);   //    884,736 B
  float*          biasf  = (float*)((char*)d_ws + 51200000 + 884736);   //        512 B
  int*            nidxT  = (int*)((char*)d_ws + 51200000 + 884736 + 512); // 21,600,000 B

  const size_t ws_need_tr = 51200000ULL + 884736ULL + 512ULL + 21600000ULL;
  const bool use_tr = (ws_size >= ws_need_tr);

  int n8 = N_ROWS * C_DIM / 8;  // 3,200,000
  k_cast<<<(n8 + 255) / 256, 256, 0, stream>>>(feats, featsB, n8);
  k_fold<<<(TAPS * 2048 + 128 + 255) / 256, 256, 0, stream>>>(conv_w, lin_w, conv_b, lin_b,
                                                              wfrag, biasf);
  if (use_tr) k_tr<<<N_ROWS / 64, 256, 0, stream>>>(nidx, nidxT);

  k_main<<<(N_ROWS + 127) / 128, 256, 0, stream>>>(
      featsB,
      use_tr ? (const int*)nidxT : nidx,
      use_tr ? 1 : TAPS,          // row stride (ints)
      use_tr ? N_ROWS : 1,        // tap stride (ints)
      wfrag, biasf, ln_w, ln_b, out);
}